// Round 6
// baseline (213.826 us; speedup 1.0000x reference)
//
#include <hip/hip_runtime.h>

// Problem constants (fixed by setup_inputs)
#define BS 4
#define NH 8
#define TT 1024         // T = 32*32
#define WROWS 1536      // 3*NH*CH
#define NOBJ 8
#define NT 65536        // per-bh tensor elems (64*1024)

// Workspace layout (short element offsets)
#define QNT_OFF  0
#define KNT_OFF  2097152
#define VNCS_OFF 4194304
#define QFT_OFF  6291456
#define KFT_OFF  8388608
#define VFT_OFF  10485760

typedef __attribute__((ext_vector_type(8))) short short8;
typedef __attribute__((ext_vector_type(4))) float v4f;

__device__ __forceinline__ short f2bf(float f) {
    unsigned u = __float_as_uint(f);
    u = (u + 0x7FFF + ((u >> 16) & 1)) >> 16;   // RNE
    return (short)u;
}
// packed f32x2 -> bf16x2 (RNE), lo = a, hi = b
__device__ __forceinline__ unsigned cvtpk(float a, float b) {
    unsigned u;
    asm("v_cvt_pk_bf16_f32 %0, %1, %2" : "=v"(u) : "v"(a), "v"(b));
    return u;
}
// 2^x via the HW transcendental (avoids glibc __exp2f name clash)
__device__ __forceinline__ float fexp2(float x) {
    float r;
    asm("v_exp_f32 %0, %1" : "=v"(r) : "v"(x));
    return r;
}
// pi-permutation of s-position within a 64-tile: s -> 4*(s&15) + (s>>4).
__device__ __forceinline__ int pi64(int s) { return 4 * (s & 15) + (s >> 4); }

__device__ __forceinline__ void get_region(const float* __restrict__ bb,
                                           int& i0, int& j0, int& hh, int& ww) {
    float x = bb[0], y = bb[1], bw = bb[2], bh = bb[3];
    float i0f = fminf(31.0f, floorf(y * 32.0f));
    float j0f = fminf(31.0f, floorf(x * 32.0f));
    float i1f = i0f + fmaxf(1.0f, ceilf(bh * 32.0f));
    float j1f = j0f + fmaxf(1.0f, ceilf(bw * 32.0f));
    i0 = (int)i0f; j0 = (int)j0f;
    int i1 = min(32, (int)i1f);
    int j1 = min(32, (int)j1f);
    hh = i1 - i0; ww = j1 - j0;
}

// ---------------------------------------------------------------------------
// Kernel 1: fused projection + layout conversion to bf16 (unchanged from R4).
// ---------------------------------------------------------------------------
__global__ __launch_bounds__(256)
void fuse_kernel(const float* __restrict__ qkv, const float* __restrict__ nEmb,
                 const float* __restrict__ pEmb, const float* __restrict__ W,
                 short* __restrict__ wsS) {
    __shared__ float WtT[64][68];
    __shared__ float En[64][64];
    __shared__ float Ep[64][64];
    short* sbuf = (short*)&WtT[0][0];   // 64x72 shorts = 9216 B, aliases WtT
    int t0 = blockIdx.x * 64;
    int r0 = blockIdx.y * 64;
    int b  = blockIdx.z;
    int tid = threadIdx.x;
    int half = tid >> 4;
    int q4 = (tid & 15) * 4;
#pragma unroll
    for (int p = 0; p < 4; ++p) {
        int rr = p * 16 + half;
        float4 w4 = *(const float4*)&W[(r0 + rr) * 64 + q4];
        WtT[q4 + 0][rr] = w4.x; WtT[q4 + 1][rr] = w4.y;
        WtT[q4 + 2][rr] = w4.z; WtT[q4 + 3][rr] = w4.w;
        int e = p * 16 + half;
        *(float4*)&En[e][q4] = *(const float4*)&nEmb[(b * 64 + e) * TT + t0 + q4];
        *(float4*)&Ep[e][q4] = *(const float4*)&pEmb[(b * 64 + e) * TT + t0 + q4];
    }
    __syncthreads();
    int tr = tid >> 4, tc = tid & 15;
    float an[4][4] = {{0.f}}, ap[4][4] = {{0.f}};
#pragma unroll 8
    for (int e = 0; e < 64; ++e) {
        float4 w4 = *(const float4*)&WtT[e][tr * 4];
        float4 n4 = *(const float4*)&En[e][tc * 4];
        float4 p4 = *(const float4*)&Ep[e][tc * 4];
        float w[4]  = {w4.x, w4.y, w4.z, w4.w};
        float nn[4] = {n4.x, n4.y, n4.z, n4.w};
        float pp[4] = {p4.x, p4.y, p4.z, p4.w};
#pragma unroll
        for (int i = 0; i < 4; ++i)
#pragma unroll
            for (int j = 0; j < 4; ++j) {
                an[i][j] += w[i] * nn[j];
                ap[i][j] += w[i] * pp[j];
            }
    }
    int sec = (r0 % 192) / 64;          // 0=q 1=k 2=v
    int h = r0 / 192, bh = b * 8 + h;
    // fold scale^2 AND log2(e) into Q (attn uses exp2)
    float sc = (sec == 0) ? 0.18033688f : 1.0f;
#pragma unroll
    for (int i = 0; i < 4; ++i) {
        int r = r0 + tr * 4 + i;
        float4 x4 = *(const float4*)&qkv[(b * WROWS + r) * TT + t0 + tc * 4];
        an[i][0] = (an[i][0] + x4.x) * sc; an[i][1] = (an[i][1] + x4.y) * sc;
        an[i][2] = (an[i][2] + x4.z) * sc; an[i][3] = (an[i][3] + x4.w) * sc;
        ap[i][0] = (ap[i][0] + x4.x) * sc; ap[i][1] = (ap[i][1] + x4.y) * sc;
        ap[i][2] = (ap[i][2] + x4.z) * sc; ap[i][3] = (ap[i][3] + x4.w) * sc;
    }
    if (sec == 2) {
        // pass 1: null V, pre-permuted [c][pi(p)] within each 64-tile
        short* Vn = wsS + VNCS_OFF + bh * NT;
        __syncthreads();
#pragma unroll
        for (int i = 0; i < 4; ++i)
#pragma unroll
            for (int j = 0; j < 4; ++j) {
                int p = tc * 4 + j;
                sbuf[(tr * 4 + i) * 72 + pi64(p)] = f2bf(an[i][j]);
            }
        __syncthreads();
#pragma unroll
        for (int rep = 0; rep < 2; ++rep) {
            int idx = rep * 256 + tid; int cl = idx >> 3, c8 = idx & 7;
            *(short8*)&Vn[cl * TT + t0 + c8 * 8] = *(const short8*)&sbuf[cl * 72 + c8 * 8];
        }
        // pass 2: fg V transposed [t][c]
        short* dst = wsS + VFT_OFF + bh * NT + t0 * 64;
        __syncthreads();
#pragma unroll
        for (int j = 0; j < 4; ++j) {
            uint2 u; u.x = cvtpk(ap[0][j], ap[1][j]); u.y = cvtpk(ap[2][j], ap[3][j]);
            *(uint2*)&sbuf[(tc * 4 + j) * 72 + tr * 4] = u;
        }
        __syncthreads();
#pragma unroll
        for (int rep = 0; rep < 2; ++rep) {
            int idx = rep * 256 + tid; int tl = idx >> 3, c8 = idx & 7;
            *(short8*)&dst[tl * 64 + c8 * 8] = *(const short8*)&sbuf[tl * 72 + c8 * 8];
        }
    } else {
        short* dn = wsS + (sec == 0 ? QNT_OFF : KNT_OFF) + bh * NT + t0 * 64;
        short* df = wsS + (sec == 0 ? QFT_OFF : KFT_OFF) + bh * NT + t0 * 64;
        __syncthreads();
#pragma unroll
        for (int j = 0; j < 4; ++j) {
            uint2 u; u.x = cvtpk(an[0][j], an[1][j]); u.y = cvtpk(an[2][j], an[3][j]);
            *(uint2*)&sbuf[(tc * 4 + j) * 72 + tr * 4] = u;
        }
        __syncthreads();
#pragma unroll
        for (int rep = 0; rep < 2; ++rep) {
            int idx = rep * 256 + tid; int tl = idx >> 3, c8 = idx & 7;
            *(short8*)&dn[tl * 64 + c8 * 8] = *(const short8*)&sbuf[tl * 72 + c8 * 8];
        }
        __syncthreads();
#pragma unroll
        for (int j = 0; j < 4; ++j) {
            uint2 u; u.x = cvtpk(ap[0][j], ap[1][j]); u.y = cvtpk(ap[2][j], ap[3][j]);
            *(uint2*)&sbuf[(tc * 4 + j) * 72 + tr * 4] = u;
        }
        __syncthreads();
#pragma unroll
        for (int rep = 0; rep < 2; ++rep) {
            int idx = rep * 256 + tid; int tl = idx >> 3, c8 = idx & 7;
            *(short8*)&df[tl * 64 + c8 * 8] = *(const short8*)&sbuf[tl * 72 + c8 * 8];
        }
    }
}

// ---------------------------------------------------------------------------
// Kernel 2: fused null + foreground attention, RESTRUCTURED:
//  - grid (32 bh, 32 rt), 128 threads (2 waves), 32 query rows per block
//    -> 1024 blocks, 4 independent blocks/CU (was 2 lockstep 4-wave blocks).
//  - bh-major grid: all 32 same-bh blocks land on XCD bh%8 -> K/V L2-hot.
//  - Null phase: ZERO barriers, zero staging. K fragments direct from KnT
//    (row-major [s][c]), V fragments direct from Vn (pre-permuted [c][pi(s)]).
//    P round-trip in wave-private LDS rows only.
//  - FG phase: K direct via tmap gather; V double-buffered in LDS with the
//    rotated pi-transpose scatter; ONE barrier per tile (was 2).
// ---------------------------------------------------------------------------
__global__ __launch_bounds__(128)
void attn_fused(const short* __restrict__ wsS, const float* __restrict__ bboxes,
                float* __restrict__ out) {
    __shared__ __align__(16) short lds[11520];   // P[32][72] + Vbuf[2][64][72]
    __shared__ unsigned short tmap[1024];
    short* Ps = lds;                    // [32][72] wave-private P rows
    short* Vb = lds + 2304;             // [2][64][72] (4608 shorts per buffer)
    float* Ot = (float*)(lds + 2304);   // [64][36] floats = 9216 B, aliases Vb

    int bh = blockIdx.x, rt = blockIdx.y;
    int b = bh >> 3, h = bh & 7;
    int t0 = rt * 32;
    int tid = threadIdx.x;              // 0..127
    int w = tid >> 6;                   // wave 0..1 (rows 16w..16w+15)
    int lane = tid & 63, ln = lane & 15, qd = lane >> 4;
    int rB = tid >> 3, c8 = tid & 7;    // stage coords: row-base 0..15, chunk 0..7

    const short* QnT = wsS + QNT_OFF + bh * NT;
    const short* KnT = wsS + KNT_OFF + bh * NT;
    const short* Vn  = wsS + VNCS_OFF + bh * NT;   // pre-permuted [c][pi]
    const short* QfT = wsS + QFT_OFF + bh * NT;
    const short* KfT = wsS + KFT_OFF + bh * NT;
    const short* VfT = wsS + VFT_OFF + bh * NT;

    // ================= Phase 1: null attention (barrier-free) =================
    short8 aq0 = *(const short8*)&QnT[(t0 + 16 * w + ln) * 64 + qd * 8];
    short8 aq1 = *(const short8*)&QnT[(t0 + 16 * w + ln) * 64 + 32 + qd * 8];
    v4f O[4]; float l[4];
#pragma unroll
    for (int r = 0; r < 4; ++r) l[r] = 0.f;
#pragma unroll
    for (int cc = 0; cc < 4; ++cc) O[cc] = (v4f){0.f, 0.f, 0.f, 0.f};
    for (int ct = 0; ct < 16; ++ct) {
        int s0 = ct * 64;
        v4f S[4];
#pragma unroll
        for (int nn = 0; nn < 4; ++nn) {
            const short* kp = &KnT[(s0 + nn * 16 + ln) * 64 + qd * 8];
            short8 b0 = *(const short8*)kp;
            short8 b1 = *(const short8*)(kp + 32);
            v4f z = (v4f){0.f, 0.f, 0.f, 0.f};
            z = __builtin_amdgcn_mfma_f32_16x16x32_bf16(aq0, b0, z, 0, 0, 0);
            z = __builtin_amdgcn_mfma_f32_16x16x32_bf16(aq1, b1, z, 0, 0, 0);
            S[nn] = z;
        }
#pragma unroll
        for (int r = 0; r < 4; ++r) {
            float e0 = fexp2(S[0][r]);
            float e1 = fexp2(S[1][r]);
            float e2 = fexp2(S[2][r]);
            float e3 = fexp2(S[3][r]);
            l[r] += (e0 + e1) + (e2 + e3);
            uint2 u; u.x = cvtpk(e0, e1); u.y = cvtpk(e2, e3);
            *(uint2*)&Ps[(w * 16 + 4 * qd + r) * 72 + 4 * ln] = u;   // cols pi(s)
        }
        short8 ap0 = *(const short8*)&Ps[(w * 16 + ln) * 72 + qd * 8];
        short8 ap1 = *(const short8*)&Ps[(w * 16 + ln) * 72 + 32 + qd * 8];
#pragma unroll
        for (int cc = 0; cc < 4; ++cc) {
            const short* vp = &Vn[(cc * 16 + ln) * TT + s0 + qd * 8];
            short8 bv0 = *(const short8*)vp;
            short8 bv1 = *(const short8*)(vp + 32);
            O[cc] = __builtin_amdgcn_mfma_f32_16x16x32_bf16(ap0, bv0, O[cc], 0, 0, 0);
            O[cc] = __builtin_amdgcn_mfma_f32_16x16x32_bf16(ap1, bv1, O[cc], 0, 0, 0);
        }
    }
    v4f Onull[4];
#pragma unroll
    for (int r = 0; r < 4; ++r) {
        float rs = l[r];
        rs += __shfl_xor(rs, 1, 64);
        rs += __shfl_xor(rs, 2, 64);
        rs += __shfl_xor(rs, 4, 64);
        rs += __shfl_xor(rs, 8, 64);
        float inv = 1.0f / rs;
#pragma unroll
        for (int cc = 0; cc < 4; ++cc) Onull[cc][r] = O[cc][r] * inv;
    }

    // ================= Phase 2: foreground objects =================
    aq0 = *(const short8*)&QfT[(t0 + 16 * w + ln) * 64 + qd * 8];
    aq1 = *(const short8*)&QfT[(t0 + 16 * w + ln) * 64 + 32 + qd * 8];
    v4f Oacc[4]; float cnt[4];
#pragma unroll
    for (int r = 0; r < 4; ++r) cnt[r] = 0.f;
#pragma unroll
    for (int cc = 0; cc < 4; ++cc) Oacc[cc] = (v4f){0.f, 0.f, 0.f, 0.f};

    for (int o = 0; o < NOBJ; ++o) {
        int i0, j0, hh, ww;
        get_region(&bboxes[(b * NOBJ + o) * 5], i0, j0, hh, ww);
        int i1 = i0 + hh;
        if (i0 > rt || i1 <= rt) continue;   // block's 32 rows = image row rt
        int R = hh * ww;
        for (int idx = tid; idx < R; idx += 128) {
            int ri = idx / ww; int rj = idx - ri * ww;
            tmap[idx] = (unsigned short)((i0 + ri) * 32 + j0 + rj);
        }
        __syncthreads();   // tmap visible; prior object's Vb reads all done
#pragma unroll
        for (int r = 0; r < 4; ++r) l[r] = 0.f;
#pragma unroll
        for (int cc = 0; cc < 4; ++cc) O[cc] = (v4f){0.f, 0.f, 0.f, 0.f};
        int nct = (R + 63) >> 6;
        short8 vreg[4];
        // prologue: stage tile 0 into buf0, prefetch tile 1
#pragma unroll
        for (int k = 0; k < 4; ++k)
            vreg[k] = *(const short8*)&VfT[(int)tmap[min(rB + 16 * k, R - 1)] * 64 + c8 * 8];
#pragma unroll
        for (int k = 0; k < 4; ++k) {
            int pK = 4 * rB + k;       // pi64(rB + 16k)
#pragma unroll
            for (int jj = 0; jj < 8; ++jj) {
                int j = (jj + c8) & 7;
                Vb[(c8 * 8 + j) * 72 + pK] = vreg[k][j];
            }
        }
        if (nct > 1) {
#pragma unroll
            for (int k = 0; k < 4; ++k)
                vreg[k] = *(const short8*)&VfT[(int)tmap[min(64 + rB + 16 * k, R - 1)] * 64 + c8 * 8];
        }
        __syncthreads();   // buf0 ready
        for (int p = 0; p < nct; ++p) {
            int sb = p * 64;
            const short* curV = Vb + (p & 1) * 4608;
            if (p + 1 < nct) {
                short* nxtV = Vb + ((p + 1) & 1) * 4608;
#pragma unroll
                for (int k = 0; k < 4; ++k) {
                    int pK = 4 * rB + k;
#pragma unroll
                    for (int jj = 0; jj < 8; ++jj) {
                        int j = (jj + c8) & 7;
                        nxtV[(c8 * 8 + j) * 72 + pK] = vreg[k][j];
                    }
                }
            }
            if (p + 2 < nct) {
                int s0 = sb + 128;
#pragma unroll
                for (int k = 0; k < 4; ++k)
                    vreg[k] = *(const short8*)&VfT[(int)tmap[min(s0 + rB + 16 * k, R - 1)] * 64 + c8 * 8];
            }
            // K via direct tmap gather + S
            v4f S[4];
#pragma unroll
            for (int nn = 0; nn < 4; ++nn) {
                int tg = tmap[min(sb + nn * 16 + ln, R - 1)];
                const short* kp = &KfT[tg * 64 + qd * 8];
                short8 b0 = *(const short8*)kp;
                short8 b1 = *(const short8*)(kp + 32);
                v4f z = (v4f){0.f, 0.f, 0.f, 0.f};
                z = __builtin_amdgcn_mfma_f32_16x16x32_bf16(aq0, b0, z, 0, 0, 0);
                z = __builtin_amdgcn_mfma_f32_16x16x32_bf16(aq1, b1, z, 0, 0, 0);
                S[nn] = z;
            }
            float v0 = (sb +  0 + ln) < R ? 1.f : 0.f;
            float v1 = (sb + 16 + ln) < R ? 1.f : 0.f;
            float v2 = (sb + 32 + ln) < R ? 1.f : 0.f;
            float v3 = (sb + 48 + ln) < R ? 1.f : 0.f;
#pragma unroll
            for (int r = 0; r < 4; ++r) {
                float e0 = fexp2(S[0][r]) * v0;
                float e1 = fexp2(S[1][r]) * v1;
                float e2 = fexp2(S[2][r]) * v2;
                float e3 = fexp2(S[3][r]) * v3;
                l[r] += (e0 + e1) + (e2 + e3);
                uint2 u; u.x = cvtpk(e0, e1); u.y = cvtpk(e2, e3);
                *(uint2*)&Ps[(w * 16 + 4 * qd + r) * 72 + 4 * ln] = u;
            }
            short8 ap0 = *(const short8*)&Ps[(w * 16 + ln) * 72 + qd * 8];
            short8 ap1 = *(const short8*)&Ps[(w * 16 + ln) * 72 + 32 + qd * 8];
#pragma unroll
            for (int cc = 0; cc < 4; ++cc) {
                short8 bv0 = *(const short8*)&curV[(cc * 16 + ln) * 72 + qd * 8];
                short8 bv1 = *(const short8*)&curV[(cc * 16 + ln) * 72 + 32 + qd * 8];
                O[cc] = __builtin_amdgcn_mfma_f32_16x16x32_bf16(ap0, bv0, O[cc], 0, 0, 0);
                O[cc] = __builtin_amdgcn_mfma_f32_16x16x32_bf16(ap1, bv1, O[cc], 0, 0, 0);
            }
            __syncthreads();   // done reading buf[p&1]; nxt writes visible
        }
        // finalize object: accumulate rows inside region (ti == rt always)
#pragma unroll
        for (int r = 0; r < 4; ++r) {
            float rs = l[r];
            rs += __shfl_xor(rs, 1, 64);
            rs += __shfl_xor(rs, 2, 64);
            rs += __shfl_xor(rs, 4, 64);
            rs += __shfl_xor(rs, 8, 64);
            float inv = 1.0f / rs;
            int tj = (16 * w + 4 * qd + r) & 31;
            bool in = (tj >= j0) && (tj < j0 + ww);
            if (in) {
                cnt[r] += 1.f;
#pragma unroll
                for (int cc = 0; cc < 4; ++cc) Oacc[cc][r] += O[cc][r] * inv;
            }
        }
    }

    // ================= Epilogue =================
    __syncthreads();   // all Vb reads done (Ot aliases Vb)
#pragma unroll
    for (int r = 0; r < 4; ++r) {
        int tl = 16 * w + 4 * qd + r;
        float icnt = cnt[r] > 0.f ? 1.0f / cnt[r] : 0.f;
#pragma unroll
        for (int cc = 0; cc < 4; ++cc) {
            float val = cnt[r] > 0.f ? Oacc[cc][r] * icnt : Onull[cc][r];
            Ot[(cc * 16 + ln) * 36 + tl] = val;
        }
    }
    __syncthreads();
    int obase = (b * 512 + h * 64) * TT + t0;
#pragma unroll
    for (int rep = 0; rep < 4; ++rep) {
        int idx = rep * 128 + tid; int c = idx >> 3, t4 = (idx & 7) * 4;
        *(float4*)&out[obase + c * TT + t4] = *(float4*)&Ot[c * 36 + t4];
    }
}

extern "C" void kernel_launch(void* const* d_in, const int* in_sizes, int n_in,
                              void* d_out, int out_size, void* d_ws, size_t ws_size,
                              hipStream_t stream) {
    const float* qkv    = (const float*)d_in[0];
    const float* bboxes = (const float*)d_in[1];
    const float* nEmb   = (const float*)d_in[2];
    const float* pEmb   = (const float*)d_in[3];
    const float* W      = (const float*)d_in[4];
    short* wsS = (short*)d_ws;
    float* out = (float*)d_out;

    fuse_kernel<<<dim3(16, 24, 4), 256, 0, stream>>>(qkv, nEmb, pEmb, W, wsS);
    attn_fused<<<dim3(32, 32), 128, 0, stream>>>(wsS, bboxes, out);
}

// Round 7
// 144.665 us; speedup vs baseline: 1.4781x; 1.4781x over previous
//
#include <hip/hip_runtime.h>

// Problem constants (fixed by setup_inputs)
#define BS 4
#define NH 8
#define TT 1024         // T = 32*32
#define WROWS 1536      // 3*NH*CH
#define NOBJ 8
#define NT 65536        // per-bh tensor elems (64*1024)

// Workspace layout (short element offsets)
#define QNT_OFF  0
#define KNT_OFF  2097152
#define VNCS_OFF 4194304
#define QFT_OFF  6291456
#define KFT_OFF  8388608
#define VFT_OFF  10485760

typedef __attribute__((ext_vector_type(8))) short short8;
typedef __attribute__((ext_vector_type(4))) float v4f;

__device__ __forceinline__ short f2bf(float f) {
    unsigned u = __float_as_uint(f);
    u = (u + 0x7FFF + ((u >> 16) & 1)) >> 16;   // RNE
    return (short)u;
}
// packed f32x2 -> bf16x2 (RNE), lo = a, hi = b
__device__ __forceinline__ unsigned cvtpk(float a, float b) {
    unsigned u;
    asm("v_cvt_pk_bf16_f32 %0, %1, %2" : "=v"(u) : "v"(a), "v"(b));
    return u;
}
// 2^x via the HW transcendental (avoids glibc __exp2f name clash)
__device__ __forceinline__ float fexp2(float x) {
    float r;
    asm("v_exp_f32 %0, %1" : "=v"(r) : "v"(x));
    return r;
}
// pi-permutation of s-position within a 64-tile: s -> 4*(s&15) + (s>>4).
__device__ __forceinline__ int pi64(int s) { return 4 * (s & 15) + (s >> 4); }

__device__ __forceinline__ void get_region(const float* __restrict__ bb,
                                           int& i0, int& j0, int& hh, int& ww) {
    float x = bb[0], y = bb[1], bw = bb[2], bh = bb[3];
    float i0f = fminf(31.0f, floorf(y * 32.0f));
    float j0f = fminf(31.0f, floorf(x * 32.0f));
    float i1f = i0f + fmaxf(1.0f, ceilf(bh * 32.0f));
    float j1f = j0f + fmaxf(1.0f, ceilf(bw * 32.0f));
    i0 = (int)i0f; j0 = (int)j0f;
    int i1 = min(32, (int)i1f);
    int j1 = min(32, (int)j1f);
    hh = i1 - i0; ww = j1 - j0;
}

// ---------------------------------------------------------------------------
// Kernel 1: fused projection + layout conversion, REWRITTEN ON MFMA.
// P[r][t] = sum_e W[r][e] * E[e][t] as 64x64x64 bf16 GEMM per block (x2 for
// null/prompt). E staged transposed bf16 [t][e] in LDS (B-frags contiguous
// ds_read_b128); W A-frags bf16 direct from global. Replaces the 2048-FMA
// per-thread fp32 VALU loop. Output layouts identical to previous rounds:
// q/k/fgV transposed [t][c]; null V pre-permuted [c][pi(p)] per 64-tile.
// Q scaled by 0.125*log2(e) so attention uses exp2.
// ---------------------------------------------------------------------------
__global__ __launch_bounds__(256)
void fuse_kernel(const float* __restrict__ qkv, const float* __restrict__ nEmb,
                 const float* __restrict__ pEmb, const float* __restrict__ W,
                 short* __restrict__ wsS) {
    __shared__ __align__(16) short Ent[64 * 72];
    __shared__ __align__(16) short Ept[64 * 72];
    __shared__ __align__(16) short sbuf[64 * 72];
    int t0 = blockIdx.x * 64;
    int r0 = blockIdx.y * 64;
    int b  = blockIdx.z;
    int tid = threadIdx.x;
    int w = tid >> 6, lane = tid & 63, ln = lane & 15, qd = lane >> 4;

    // stage E (null & prompt) transposed to bf16 [t][e], pitch 72
    {
        int e  = tid >> 4;
        int t4 = (tid & 15) * 4;
#pragma unroll
        for (int p = 0; p < 4; ++p) {
            int ee = p * 16 + e;
            float4 n4 = *(const float4*)&nEmb[(b * 64 + ee) * TT + t0 + t4];
            float4 p4 = *(const float4*)&pEmb[(b * 64 + ee) * TT + t0 + t4];
            Ent[(t4 + 0) * 72 + ee] = f2bf(n4.x); Ent[(t4 + 1) * 72 + ee] = f2bf(n4.y);
            Ent[(t4 + 2) * 72 + ee] = f2bf(n4.z); Ent[(t4 + 3) * 72 + ee] = f2bf(n4.w);
            Ept[(t4 + 0) * 72 + ee] = f2bf(p4.x); Ept[(t4 + 1) * 72 + ee] = f2bf(p4.y);
            Ept[(t4 + 2) * 72 + ee] = f2bf(p4.z); Ept[(t4 + 3) * 72 + ee] = f2bf(p4.w);
        }
    }
    // W A-fragments (bf16) direct from global: lane ln -> row r0+16w+ln
    short8 aw0, aw1;
    {
        const float* wp = &W[(r0 + 16 * w + ln) * 64 + qd * 8];
        float4 f0 = *(const float4*)wp;
        float4 f1 = *(const float4*)(wp + 4);
        float4 f2 = *(const float4*)(wp + 32);
        float4 f3 = *(const float4*)(wp + 36);
        uint4 u0, u1;
        u0.x = cvtpk(f0.x, f0.y); u0.y = cvtpk(f0.z, f0.w);
        u0.z = cvtpk(f1.x, f1.y); u0.w = cvtpk(f1.z, f1.w);
        u1.x = cvtpk(f2.x, f2.y); u1.y = cvtpk(f2.z, f2.w);
        u1.z = cvtpk(f3.x, f3.y); u1.w = cvtpk(f3.z, f3.w);
        aw0 = *(short8*)&u0; aw1 = *(short8*)&u1;
    }
    __syncthreads();
    // MFMA: D[row=16w+4qd+i][col=nn*16+ln] = sum_e W[row][e]*E[e][col]
    v4f accN[4], accP[4];
#pragma unroll
    for (int nn = 0; nn < 4; ++nn) {
        const short* bp = &Ent[(nn * 16 + ln) * 72 + qd * 8];
        short8 b0 = *(const short8*)bp;
        short8 b1 = *(const short8*)(bp + 32);
        v4f z = (v4f){0.f, 0.f, 0.f, 0.f};
        z = __builtin_amdgcn_mfma_f32_16x16x32_bf16(aw0, b0, z, 0, 0, 0);
        z = __builtin_amdgcn_mfma_f32_16x16x32_bf16(aw1, b1, z, 0, 0, 0);
        accN[nn] = z;
        const short* cp = &Ept[(nn * 16 + ln) * 72 + qd * 8];
        short8 c0 = *(const short8*)cp;
        short8 c1 = *(const short8*)(cp + 32);
        v4f y = (v4f){0.f, 0.f, 0.f, 0.f};
        y = __builtin_amdgcn_mfma_f32_16x16x32_bf16(aw0, c0, y, 0, 0, 0);
        y = __builtin_amdgcn_mfma_f32_16x16x32_bf16(aw1, c1, y, 0, 0, 0);
        accP[nn] = y;
    }
    // add qkv + scale
    int sec = (r0 % 192) / 64;          // 0=q 1=k 2=v
    int h = r0 / 192, bh = b * 8 + h;
    float sc = (sec == 0) ? 0.18033688f : 1.0f;   // 0.125*log2e folded into Q
    float xan[4][4], xap[4][4];                    // [nn][i]
#pragma unroll
    for (int nn = 0; nn < 4; ++nn)
#pragma unroll
        for (int i = 0; i < 4; ++i) {
            int r = r0 + 16 * w + 4 * qd + i;
            float x = qkv[(b * WROWS + r) * TT + t0 + nn * 16 + ln];
            xan[nn][i] = (accN[nn][i] + x) * sc;
            xap[nn][i] = (accP[nn][i] + x) * sc;
        }

    if (sec == 2) {
        // pass 1: null V pre-permuted [c][pi(p)]: row c = 16w+4qd+i, col 4ln+nn
        short* Vn = wsS + VNCS_OFF + bh * NT;
#pragma unroll
        for (int nn = 0; nn < 4; ++nn)
#pragma unroll
            for (int i = 0; i < 4; ++i)
                sbuf[(16 * w + 4 * qd + i) * 72 + 4 * ln + nn] = f2bf(xan[nn][i]);
        __syncthreads();
#pragma unroll
        for (int rep = 0; rep < 2; ++rep) {
            int idx = rep * 256 + tid; int cl = idx >> 3, c8 = idx & 7;
            *(short8*)&Vn[cl * TT + t0 + c8 * 8] = *(const short8*)&sbuf[cl * 72 + c8 * 8];
        }
        __syncthreads();
        // pass 2: fg V transposed [t][c]: row t = nn*16+ln, cols 16w+4qd..+3
        short* dst = wsS + VFT_OFF + bh * NT + t0 * 64;
#pragma unroll
        for (int nn = 0; nn < 4; ++nn) {
            uint2 u; u.x = cvtpk(xap[nn][0], xap[nn][1]); u.y = cvtpk(xap[nn][2], xap[nn][3]);
            *(uint2*)&sbuf[(nn * 16 + ln) * 72 + 16 * w + 4 * qd] = u;
        }
        __syncthreads();
#pragma unroll
        for (int rep = 0; rep < 2; ++rep) {
            int idx = rep * 256 + tid; int tl = idx >> 3, c8 = idx & 7;
            *(short8*)&dst[tl * 64 + c8 * 8] = *(const short8*)&sbuf[tl * 72 + c8 * 8];
        }
    } else {
        short* dn = wsS + (sec == 0 ? QNT_OFF : KNT_OFF) + bh * NT + t0 * 64;
        short* df = wsS + (sec == 0 ? QFT_OFF : KFT_OFF) + bh * NT + t0 * 64;
        // pass 1: null, transposed [t][c]
#pragma unroll
        for (int nn = 0; nn < 4; ++nn) {
            uint2 u; u.x = cvtpk(xan[nn][0], xan[nn][1]); u.y = cvtpk(xan[nn][2], xan[nn][3]);
            *(uint2*)&sbuf[(nn * 16 + ln) * 72 + 16 * w + 4 * qd] = u;
        }
        __syncthreads();
#pragma unroll
        for (int rep = 0; rep < 2; ++rep) {
            int idx = rep * 256 + tid; int tl = idx >> 3, c8 = idx & 7;
            *(short8*)&dn[tl * 64 + c8 * 8] = *(const short8*)&sbuf[tl * 72 + c8 * 8];
        }
        __syncthreads();
        // pass 2: fg, transposed [t][c]
#pragma unroll
        for (int nn = 0; nn < 4; ++nn) {
            uint2 u; u.x = cvtpk(xap[nn][0], xap[nn][1]); u.y = cvtpk(xap[nn][2], xap[nn][3]);
            *(uint2*)&sbuf[(nn * 16 + ln) * 72 + 16 * w + 4 * qd] = u;
        }
        __syncthreads();
#pragma unroll
        for (int rep = 0; rep < 2; ++rep) {
            int idx = rep * 256 + tid; int tl = idx >> 3, c8 = idx & 7;
            *(short8*)&df[tl * 64 + c8 * 8] = *(const short8*)&sbuf[tl * 72 + c8 * 8];
        }
    }
}

// ---------------------------------------------------------------------------
// Kernel 2: fused null + foreground attention — VERBATIM round-4 version
// (verified 65 us, 108 VGPR, no spill). 256 thr, 4 waves, LDS-staged K/V,
// pi-permuted P via cvt_pk + ds_write_b64, v_exp_f32 softmax.
// ---------------------------------------------------------------------------
__global__ __launch_bounds__(256)
void attn_fused(const short* __restrict__ wsS, const float* __restrict__ bboxes,
                float* __restrict__ out) {
    __shared__ __align__(16) short lds[13824];
    __shared__ unsigned short tmap[1024];
    short* Qs = lds;            // [64][72], aliased as Ps (wave-private rows)
    short* Ks = lds + 4608;     // [64][72]  ([s][c])
    short* Vs = lds + 9216;     // [64][72]  ([c][pi(s)])
    int rt = blockIdx.x, bh = blockIdx.y;
    int b = bh >> 3, h = bh & 7;
    int t0 = rt * 64;
    int tid = threadIdx.x;
    int w = tid >> 6, lane = tid & 63, ln = lane & 15, qd = lane >> 4;
    const short* QnT = wsS + QNT_OFF + bh * NT;
    const short* KnT = wsS + KNT_OFF + bh * NT;
    const short* Vn  = wsS + VNCS_OFF + bh * NT;   // pre-permuted [c][pi]
    const short* QfT = wsS + QFT_OFF + bh * NT;
    const short* KfT = wsS + KFT_OFF + bh * NT;
    const short* VfT = wsS + VFT_OFF + bh * NT;
    int sidx = tid, scell = sidx >> 3, sc8 = sidx & 7;      // staging coords lo
    int sidx2 = 256 + tid, scell2 = sidx2 >> 3, sc82 = sidx2 & 7;

    // ================= Phase 1: null attention =================
    *(short8*)&Qs[scell * 72 + sc8 * 8]  = *(const short8*)&QnT[(t0 + scell) * 64 + sc8 * 8];
    *(short8*)&Qs[scell2 * 72 + sc82 * 8] = *(const short8*)&QnT[(t0 + scell2) * 64 + sc82 * 8];
    __syncthreads();
    short8 aq0 = *(const short8*)&Qs[(16 * w + ln) * 72 + qd * 8];
    short8 aq1 = *(const short8*)&Qs[(16 * w + ln) * 72 + 32 + qd * 8];
    v4f O[4]; float l[4];
#pragma unroll
    for (int r = 0; r < 4; ++r) l[r] = 0.f;
#pragma unroll
    for (int cc = 0; cc < 4; ++cc) O[cc] = (v4f){0.f, 0.f, 0.f, 0.f};
    short8 kreg[2], vreg[2];
    kreg[0] = *(const short8*)&KnT[scell * 64 + sc8 * 8];
    kreg[1] = *(const short8*)&KnT[scell2 * 64 + sc82 * 8];
    vreg[0] = *(const short8*)&Vn[scell * TT + sc8 * 8];
    vreg[1] = *(const short8*)&Vn[scell2 * TT + sc82 * 8];
    for (int ct = 0; ct < 16; ++ct) {
        __syncthreads();
        *(short8*)&Ks[scell * 72 + sc8 * 8]  = kreg[0];
        *(short8*)&Ks[scell2 * 72 + sc82 * 8] = kreg[1];
        *(short8*)&Vs[scell * 72 + sc8 * 8]  = vreg[0];     // Vn already [c][pi]
        *(short8*)&Vs[scell2 * 72 + sc82 * 8] = vreg[1];
        __syncthreads();
        if (ct < 15) {
            int s0 = (ct + 1) * 64;
            kreg[0] = *(const short8*)&KnT[(s0 + scell) * 64 + sc8 * 8];
            kreg[1] = *(const short8*)&KnT[(s0 + scell2) * 64 + sc82 * 8];
            vreg[0] = *(const short8*)&Vn[scell * TT + s0 + sc8 * 8];
            vreg[1] = *(const short8*)&Vn[scell2 * TT + s0 + sc82 * 8];
        }
        v4f S[4];
#pragma unroll
        for (int nn = 0; nn < 4; ++nn) {
            short8 b0 = *(const short8*)&Ks[(nn * 16 + ln) * 72 + qd * 8];
            short8 b1 = *(const short8*)&Ks[(nn * 16 + ln) * 72 + 32 + qd * 8];
            v4f z = (v4f){0.f, 0.f, 0.f, 0.f};
            z = __builtin_amdgcn_mfma_f32_16x16x32_bf16(aq0, b0, z, 0, 0, 0);
            z = __builtin_amdgcn_mfma_f32_16x16x32_bf16(aq1, b1, z, 0, 0, 0);
            S[nn] = z;
        }
#pragma unroll
        for (int r = 0; r < 4; ++r) {
            float e0 = fexp2(S[0][r]);
            float e1 = fexp2(S[1][r]);
            float e2 = fexp2(S[2][r]);
            float e3 = fexp2(S[3][r]);
            l[r] += (e0 + e1) + (e2 + e3);
            uint2 u; u.x = cvtpk(e0, e1); u.y = cvtpk(e2, e3);
            *(uint2*)&Qs[(w * 16 + 4 * qd + r) * 72 + 4 * ln] = u;   // cols pi(s)
        }
        short8 ap0 = *(const short8*)&Qs[(w * 16 + ln) * 72 + qd * 8];
        short8 ap1 = *(const short8*)&Qs[(w * 16 + ln) * 72 + 32 + qd * 8];
#pragma unroll
        for (int cc = 0; cc < 4; ++cc) {
            short8 bv0 = *(const short8*)&Vs[(cc * 16 + ln) * 72 + qd * 8];
            short8 bv1 = *(const short8*)&Vs[(cc * 16 + ln) * 72 + 32 + qd * 8];
            O[cc] = __builtin_amdgcn_mfma_f32_16x16x32_bf16(ap0, bv0, O[cc], 0, 0, 0);
            O[cc] = __builtin_amdgcn_mfma_f32_16x16x32_bf16(ap1, bv1, O[cc], 0, 0, 0);
        }
    }
    v4f Onull[4];
#pragma unroll
    for (int r = 0; r < 4; ++r) {
        float rs = l[r];
        rs += __shfl_xor(rs, 1, 64);
        rs += __shfl_xor(rs, 2, 64);
        rs += __shfl_xor(rs, 4, 64);
        rs += __shfl_xor(rs, 8, 64);
        float inv = 1.0f / rs;
#pragma unroll
        for (int cc = 0; cc < 4; ++cc) Onull[cc][r] = O[cc][r] * inv;
    }

    // ================= Phase 2: foreground objects =================
    __syncthreads();
    *(short8*)&Qs[scell * 72 + sc8 * 8]  = *(const short8*)&QfT[(t0 + scell) * 64 + sc8 * 8];
    *(short8*)&Qs[scell2 * 72 + sc82 * 8] = *(const short8*)&QfT[(t0 + scell2) * 64 + sc82 * 8];
    __syncthreads();
    aq0 = *(const short8*)&Qs[(16 * w + ln) * 72 + qd * 8];
    aq1 = *(const short8*)&Qs[(16 * w + ln) * 72 + 32 + qd * 8];
    v4f Oacc[4]; float cnt[4];
#pragma unroll
    for (int r = 0; r < 4; ++r) cnt[r] = 0.f;
#pragma unroll
    for (int cc = 0; cc < 4; ++cc) Oacc[cc] = (v4f){0.f, 0.f, 0.f, 0.f};

    for (int o = 0; o < NOBJ; ++o) {
        int i0, j0, hh, ww;
        get_region(&bboxes[(b * NOBJ + o) * 5], i0, j0, hh, ww);
        int i1 = i0 + hh;
        if (i0 > 2 * rt + 1 || i1 <= 2 * rt) continue;   // uniform per block
        int R = hh * ww;
        for (int idx = tid; idx < R; idx += 256) {
            int ri = idx / ww; int rj = idx - ri * ww;
            tmap[idx] = (unsigned short)((i0 + ri) * 32 + j0 + rj);
        }
        __syncthreads();
#pragma unroll
        for (int r = 0; r < 4; ++r) l[r] = 0.f;
#pragma unroll
        for (int cc = 0; cc < 4; ++cc) O[cc] = (v4f){0.f, 0.f, 0.f, 0.f};
        int nct = (R + 63) >> 6;
        {
            int tA = tmap[min(scell, R - 1)];
            int tB = tmap[min(scell2, R - 1)];
            kreg[0] = *(const short8*)&KfT[tA * 64 + sc8 * 8];
            kreg[1] = *(const short8*)&KfT[tB * 64 + sc82 * 8];
            vreg[0] = *(const short8*)&VfT[tA * 64 + sc8 * 8];
            vreg[1] = *(const short8*)&VfT[tB * 64 + sc82 * 8];
        }
        int pA = pi64(scell), pB = pi64(scell2);
        for (int ct = 0; ct < nct; ++ct) {
            int sb = ct * 64;
            __syncthreads();
            *(short8*)&Ks[scell * 72 + sc8 * 8]  = kreg[0];
            *(short8*)&Ks[scell2 * 72 + sc82 * 8] = kreg[1];
            // rotated transpose scatter into Vs [c][pi(s)]
#pragma unroll
            for (int jj = 0; jj < 8; ++jj) {
                int j = (jj + sc8) & 7;
                Vs[(sc8 * 8 + j) * 72 + pA] = vreg[0][j];
            }
#pragma unroll
            for (int jj = 0; jj < 8; ++jj) {
                int j = (jj + sc82) & 7;
                Vs[(sc82 * 8 + j) * 72 + pB] = vreg[1][j];
            }
            __syncthreads();
            if (ct + 1 < nct) {
                int s0 = sb + 64;
                int tA = tmap[min(s0 + scell, R - 1)];
                int tB = tmap[min(s0 + scell2, R - 1)];
                kreg[0] = *(const short8*)&KfT[tA * 64 + sc8 * 8];
                kreg[1] = *(const short8*)&KfT[tB * 64 + sc82 * 8];
                vreg[0] = *(const short8*)&VfT[tA * 64 + sc8 * 8];
                vreg[1] = *(const short8*)&VfT[tB * 64 + sc82 * 8];
            }
            v4f S[4];
#pragma unroll
            for (int nn = 0; nn < 4; ++nn) {
                short8 b0 = *(const short8*)&Ks[(nn * 16 + ln) * 72 + qd * 8];
                short8 b1 = *(const short8*)&Ks[(nn * 16 + ln) * 72 + 32 + qd * 8];
                v4f z = (v4f){0.f, 0.f, 0.f, 0.f};
                z = __builtin_amdgcn_mfma_f32_16x16x32_bf16(aq0, b0, z, 0, 0, 0);
                z = __builtin_amdgcn_mfma_f32_16x16x32_bf16(aq1, b1, z, 0, 0, 0);
                S[nn] = z;
            }
            float v0 = (sb +  0 + ln) < R ? 1.f : 0.f;
            float v1 = (sb + 16 + ln) < R ? 1.f : 0.f;
            float v2 = (sb + 32 + ln) < R ? 1.f : 0.f;
            float v3 = (sb + 48 + ln) < R ? 1.f : 0.f;
#pragma unroll
            for (int r = 0; r < 4; ++r) {
                float e0 = fexp2(S[0][r]) * v0;
                float e1 = fexp2(S[1][r]) * v1;
                float e2 = fexp2(S[2][r]) * v2;
                float e3 = fexp2(S[3][r]) * v3;
                l[r] += (e0 + e1) + (e2 + e3);
                uint2 u; u.x = cvtpk(e0, e1); u.y = cvtpk(e2, e3);
                *(uint2*)&Qs[(w * 16 + 4 * qd + r) * 72 + 4 * ln] = u;
            }
            short8 ap0 = *(const short8*)&Qs[(w * 16 + ln) * 72 + qd * 8];
            short8 ap1 = *(const short8*)&Qs[(w * 16 + ln) * 72 + 32 + qd * 8];
#pragma unroll
            for (int cc = 0; cc < 4; ++cc) {
                short8 bv0 = *(const short8*)&Vs[(cc * 16 + ln) * 72 + qd * 8];
                short8 bv1 = *(const short8*)&Vs[(cc * 16 + ln) * 72 + 32 + qd * 8];
                O[cc] = __builtin_amdgcn_mfma_f32_16x16x32_bf16(ap0, bv0, O[cc], 0, 0, 0);
                O[cc] = __builtin_amdgcn_mfma_f32_16x16x32_bf16(ap1, bv1, O[cc], 0, 0, 0);
            }
        }
        // finalize object: accumulate rows inside region
#pragma unroll
        for (int r = 0; r < 4; ++r) {
            float rs = l[r];
            rs += __shfl_xor(rs, 1, 64);
            rs += __shfl_xor(rs, 2, 64);
            rs += __shfl_xor(rs, 4, 64);
            rs += __shfl_xor(rs, 8, 64);
            float inv = 1.0f / rs;
            int t = t0 + 16 * w + 4 * qd + r;
            int ti = t >> 5, tj = t & 31;
            bool in = (ti >= i0) && (ti < i1) && (tj >= j0) && (tj < j0 + ww);
            if (in) {
                cnt[r] += 1.f;
#pragma unroll
                for (int cc = 0; cc < 4; ++cc) Oacc[cc][r] += O[cc][r] * inv;
            }
        }
    }

    // ================= Epilogue =================
    __syncthreads();
    float* Ot = (float*)lds;   // [64][68] floats = 17408 B (fits in 27648 B)
#pragma unroll
    for (int r = 0; r < 4; ++r) {
        int tl = 16 * w + 4 * qd + r;
        float icnt = cnt[r] > 0.f ? 1.0f / cnt[r] : 0.f;
#pragma unroll
        for (int cc = 0; cc < 4; ++cc) {
            float val = cnt[r] > 0.f ? Oacc[cc][r] * icnt : Onull[cc][r];
            Ot[(cc * 16 + ln) * 68 + tl] = val;
        }
    }
    __syncthreads();
    int obase = (b * 512 + h * 64) * TT + t0;
#pragma unroll
    for (int rep = 0; rep < 4; ++rep) {
        int idx = rep * 256 + tid; int c = idx >> 4, t4 = (idx & 15) * 4;
        *(float4*)&out[obase + c * TT + t4] = *(float4*)&Ot[c * 68 + t4];
    }
}

extern "C" void kernel_launch(void* const* d_in, const int* in_sizes, int n_in,
                              void* d_out, int out_size, void* d_ws, size_t ws_size,
                              hipStream_t stream) {
    const float* qkv    = (const float*)d_in[0];
    const float* bboxes = (const float*)d_in[1];
    const float* nEmb   = (const float*)d_in[2];
    const float* pEmb   = (const float*)d_in[3];
    const float* W      = (const float*)d_in[4];
    short* wsS = (short*)d_ws;
    float* out = (float*)d_out;

    fuse_kernel<<<dim3(16, 24, 4), 256, 0, stream>>>(qkv, nEmb, pEmb, W, wsS);
    attn_fused<<<dim3(16, 32), 256, 0, stream>>>(wsS, bboxes, out);
}